// Round 6
// baseline (10139.315 us; speedup 1.0000x reference)
//
#include <hip/hip_runtime.h>
#include <hip/hip_bf16.h>

typedef __hip_bfloat16 bf16;

#define NH   16
#define HD   128
#define SEQ  2048
#define BB   2
#define HID  2048

// ln(10000)/64
#define ROPE_C 0.14391156856f

// ---------- helpers ----------

// Load 8 bf16 (16B, aligned) and widen to 8 floats.
__device__ __forceinline__ void unpack8(const bf16* p, float* f) {
    uint4 u = *reinterpret_cast<const uint4*>(p);
    const unsigned* w = reinterpret_cast<const unsigned*>(&u);
#pragma unroll
    for (int i = 0; i < 4; ++i) {
        f[2*i]   = __uint_as_float(w[i] << 16);          // low bf16
        f[2*i+1] = __uint_as_float(w[i] & 0xffff0000u);  // high bf16
    }
}

// Stage 16 bf16 from global into fp32 LDS.
__device__ __forceinline__ void stage16_bf16(const bf16* g, float* lds) {
    float tmp[8];
    unpack8(g, tmp);
    *reinterpret_cast<float4*>(lds)     = *reinterpret_cast<float4*>(&tmp[0]);
    *reinterpret_cast<float4*>(lds + 4) = *reinterpret_cast<float4*>(&tmp[4]);
    unpack8(g + 8, tmp);
    *reinterpret_cast<float4*>(lds + 8)  = *reinterpret_cast<float4*>(&tmp[0]);
    *reinterpret_cast<float4*>(lds + 12) = *reinterpret_cast<float4*>(&tmp[4]);
}

// Stage 16 fp32 from global into fp32 LDS (4x float4).
__device__ __forceinline__ void stage16_f32(const float* g, float* lds) {
    const float4* s = reinterpret_cast<const float4*>(g);
    float4* d = reinterpret_cast<float4*>(lds);
    d[0]=s[0]; d[1]=s[1]; d[2]=s[2]; d[3]=s[3];
}

// ---------- Q projection + fused RoPE ----------
// C[M,2048](bf16) = A[M,2048](f32) * Wq[2048,2048]^T(f32), 128x128 tile, 8x8/thread.
// Each block owns one full head (col0 = h*128), so rope pairs (d, d+64)
// are acc[i][j] and acc[i][j+4] in the SAME thread.
__global__ __launch_bounds__(256) void gemm_q_rope(const float* __restrict__ A,
                                                   const float* __restrict__ W,
                                                   bf16* __restrict__ C) {
    __shared__ float As[128][36];
    __shared__ float Bs[128][36];
    const int tid = threadIdx.x;
    const int tx = tid & 15, ty = tid >> 4;
    const int row0 = blockIdx.y * 128;
    const int col0 = blockIdx.x * 128;
    const int sr = tid >> 1;        // 0..127
    const int sc = (tid & 1) * 16;  // 0 or 16
    float acc[8][8] = {};
    for (int k0 = 0; k0 < HID; k0 += 32) {
        stage16_f32(A + (size_t)(row0 + sr) * HID + k0 + sc, &As[sr][sc]);
        stage16_f32(W + (size_t)(col0 + sr) * HID + k0 + sc, &Bs[sr][sc]);
        __syncthreads();
#pragma unroll
        for (int kk = 0; kk < 32; kk += 4) {
            float4 a[8], b[8];
#pragma unroll
            for (int i = 0; i < 8; ++i) a[i] = *reinterpret_cast<const float4*>(&As[ty + 16*i][kk]);
#pragma unroll
            for (int j = 0; j < 8; ++j) b[j] = *reinterpret_cast<const float4*>(&Bs[tx + 16*j][kk]);
#pragma unroll
            for (int i = 0; i < 8; ++i)
#pragma unroll
                for (int j = 0; j < 8; ++j)
                    acc[i][j] += a[i].x*b[j].x + a[i].y*b[j].y + a[i].z*b[j].z + a[i].w*b[j].w;
        }
        __syncthreads();
    }
    // epilogue: rope pairs (d, d+64), d = tx+16*j (j<4), token s = row & 2047
#pragma unroll
    for (int i = 0; i < 8; ++i) {
        const int r = row0 + ty + 16*i;
        const int s = r & (SEQ - 1);
        bf16* crow = C + (size_t)r * HID + col0;
#pragma unroll
        for (int j = 0; j < 4; ++j) {
            const int d = tx + 16*j;
            const float invf = expf(-(float)d * ROPE_C);
            float sn, cs;
            sincosf((float)s * invf, &sn, &cs);
            const float x1 = acc[i][j], x2 = acc[i][j+4];
            crow[d]      = __float2bfloat16(x1*cs - x2*sn);
            crow[d + 64] = __float2bfloat16(x2*cs + x1*sn);
        }
    }
}

// ---------- K/V projection, 64x128 tile, f32 in / f32 out; K gets fused RoPE ----------
// grid (2, 64): blockIdx.x==0 -> K (roped), ==1 -> V (plain).
__global__ __launch_bounds__(256) void gemm_kv_rope(const float* __restrict__ A,
                                                    const float* __restrict__ Wk,
                                                    const float* __restrict__ Wv,
                                                    float* __restrict__ Ck,
                                                    float* __restrict__ Cv) {
    __shared__ float As[64][68];
    __shared__ float Bs[128][68];
    const int tid = threadIdx.x;
    const int tx = tid & 15, ty = tid >> 4;
    const int row0 = blockIdx.y * 64;
    const bool is_v = (blockIdx.x != 0);
    const float* W = is_v ? Wv : Wk;
    float* C       = is_v ? Cv : Ck;
    const int sr = tid >> 2;        // 0..63
    const int sc = (tid & 3) * 16;  // 0,16,32,48
    const int br = tid >> 1;        // 0..127
    const int bc = (tid & 1) * 16;  // 0 or 16
    float acc[4][8] = {};
    for (int k0 = 0; k0 < HID; k0 += 64) {
        stage16_f32(A + (size_t)(row0 + sr) * HID + k0 + sc, &As[sr][sc]);
        stage16_f32(W + (size_t)br * HID + k0 + bc,      &Bs[br][bc]);
        stage16_f32(W + (size_t)br * HID + k0 + bc + 32, &Bs[br][bc + 32]);
        __syncthreads();
#pragma unroll
        for (int kk = 0; kk < 64; kk += 4) {
            float4 a[4], b[8];
#pragma unroll
            for (int i = 0; i < 4; ++i) a[i] = *reinterpret_cast<const float4*>(&As[ty + 16*i][kk]);
#pragma unroll
            for (int j = 0; j < 8; ++j) b[j] = *reinterpret_cast<const float4*>(&Bs[tx + 16*j][kk]);
#pragma unroll
            for (int i = 0; i < 4; ++i)
#pragma unroll
                for (int j = 0; j < 8; ++j)
                    acc[i][j] += a[i].x*b[j].x + a[i].y*b[j].y + a[i].z*b[j].z + a[i].w*b[j].w;
        }
        __syncthreads();
    }
#pragma unroll
    for (int i = 0; i < 4; ++i) {
        const int r = row0 + ty + 16*i;
        float* crow = C + (size_t)r * HD;
        if (is_v) {
#pragma unroll
            for (int j = 0; j < 8; ++j)
                crow[tx + 16*j] = acc[i][j];
        } else {
            const int s = r & (SEQ - 1);
#pragma unroll
            for (int j = 0; j < 4; ++j) {
                const int d = tx + 16*j;
                const float invf = expf(-(float)d * ROPE_C);
                float sn, cs;
                sincosf((float)s * invf, &sn, &cs);
                const float x1 = acc[i][j], x2 = acc[i][j+4];
                crow[d]      = x1*cs - x2*sn;
                crow[d + 64] = x2*cs + x1*sn;
            }
        }
    }
}

// ---------- attention: ONE WAVE PER QUERY ROW, no LDS, no barriers ----------
// q: bf16 [B,S,H]; k,v: fp32 [B,S,HD] (the final output buffers); out: bf16.
__global__ __launch_bounds__(256) void attn_wave(const bf16* __restrict__ q,
                                                 const float* __restrict__ kr,
                                                 const float* __restrict__ vv,
                                                 bf16* __restrict__ out) {
    const int wave = threadIdx.x >> 6;          // 0..3
    const int lane = threadIdx.x & 63;
    const int row  = blockIdx.x * 4 + wave;     // ((b*NH + h) << 11) + s
    const int s = row & (SEQ - 1);
    const int h = (row >> 11) & (NH - 1);
    const int b = row >> 15;

    const size_t qbase = ((size_t)(b * SEQ + s)) * HID + h * HD;
    const float q0 = __bfloat162float(q[qbase + lane]);
    const float q1 = __bfloat162float(q[qbase + lane + 64]);

    const float scale = 0.088388347648318433f;  // 1/sqrt(128)
    float m = -1e30f, l = 0.f, o0 = 0.f, o1 = 0.f;

    const float* kb = kr + (size_t)b * SEQ * HD;
    const float* vb = vv + (size_t)b * SEQ * HD;

    for (int t = 0; t < SEQ; ++t) {
        const size_t tb = (size_t)t * HD;
        const float k0 = kb[tb + lane];
        const float k1 = kb[tb + lane + 64];
        float part = q0 * k0 + q1 * k1;
        part += __shfl_xor(part, 1);
        part += __shfl_xor(part, 2);
        part += __shfl_xor(part, 4);
        part += __shfl_xor(part, 8);
        part += __shfl_xor(part, 16);
        part += __shfl_xor(part, 32);
        const float sc = part * scale;          // identical in all 64 lanes

        const float mn = fmaxf(m, sc);
        const float a  = __expf(m - mn);
        const float p  = __expf(sc - mn);
        const float v0 = vb[tb + lane];
        const float v1 = vb[tb + lane + 64];
        l  = l * a + p;
        o0 = o0 * a + p * v0;
        o1 = o1 * a + p * v1;
        m  = mn;
    }

    const float inv = 1.f / l;
    out[qbase + lane]      = __float2bfloat16(o0 * inv);
    out[qbase + lane + 64] = __float2bfloat16(o1 * inv);
}

// ---------- final projection: C(f32) = A(bf16) * Wo(f32)^T ----------
__global__ __launch_bounds__(256) void gemm_bf16A(const bf16* __restrict__ A,
                                                  const float* __restrict__ W,
                                                  float* __restrict__ C) {
    __shared__ float As[128][36];
    __shared__ float Bs[128][36];
    const int tid = threadIdx.x;
    const int tx = tid & 15, ty = tid >> 4;
    const int row0 = blockIdx.y * 128;
    const int col0 = blockIdx.x * 128;
    const int sr = tid >> 1;
    const int sc = (tid & 1) * 16;
    float acc[8][8] = {};
    for (int k0 = 0; k0 < HID; k0 += 32) {
        stage16_bf16(A + (size_t)(row0 + sr) * HID + k0 + sc, &As[sr][sc]);
        stage16_f32 (W + (size_t)(col0 + sr) * HID + k0 + sc, &Bs[sr][sc]);
        __syncthreads();
#pragma unroll
        for (int kk = 0; kk < 32; kk += 4) {
            float4 a[8], b[8];
#pragma unroll
            for (int i = 0; i < 8; ++i) a[i] = *reinterpret_cast<const float4*>(&As[ty + 16*i][kk]);
#pragma unroll
            for (int j = 0; j < 8; ++j) b[j] = *reinterpret_cast<const float4*>(&Bs[tx + 16*j][kk]);
#pragma unroll
            for (int i = 0; i < 8; ++i)
#pragma unroll
                for (int j = 0; j < 8; ++j)
                    acc[i][j] += a[i].x*b[j].x + a[i].y*b[j].y + a[i].z*b[j].z + a[i].w*b[j].w;
        }
        __syncthreads();
    }
#pragma unroll
    for (int i = 0; i < 8; ++i) {
        const size_t r = row0 + ty + 16*i;
#pragma unroll
        for (int j = 0; j < 8; ++j)
            C[r * HID + col0 + tx + 16*j] = acc[i][j];
    }
}

// ---------- launch ----------
extern "C" void kernel_launch(void* const* d_in, const int* in_sizes, int n_in,
                              void* d_out, int out_size, void* d_ws, size_t ws_size,
                              hipStream_t stream) {
    // inputs AND outputs are float32 (round-5 post-mortem: bf16 input casts -> NaN,
    // fp32-offset mislayout -> the bit-stable 4.2159; harness reads fp32).
    const float* hs = (const float*)d_in[0];
    const float* Wq = (const float*)d_in[1];
    const float* Wk = (const float*)d_in[2];
    const float* Wv = (const float*)d_in[3];
    const float* Wo = (const float*)d_in[4];

    float* out      = (float*)d_out;
    float* out_attn = out;                         // [B,S,H]    8388608 f32
    float* out_k    = out + 8388608;               // [B,1,S,HD]  524288 f32
    float* out_v    = out + 8388608 + 524288;      // [B,1,S,HD]  524288 f32

    // Roped q (bf16) stashed in the first 16.78 MB of d_out's attn region;
    // fully consumed by attn_wave before gemm_bf16A overwrites it (same stream).
    bf16* qbuf     = (bf16*)d_out;                 // [B,S,H] bf16, bytes 0..16.78M
    bf16* attn_out = (bf16*)d_ws;                  // [B,S,H] bf16, 16.78 MB

    dim3 blk(256);
    gemm_q_rope <<<dim3(HID/128, (BB*SEQ)/128), blk, 0, stream>>>(hs, Wq, qbuf);
    gemm_kv_rope<<<dim3(2,       (BB*SEQ)/64 ), blk, 0, stream>>>(hs, Wk, Wv, out_k, out_v);
    attn_wave   <<<dim3((BB*NH*SEQ)/4),         blk, 0, stream>>>(qbuf, out_k, out_v, attn_out);
    gemm_bf16A  <<<dim3(HID/128, (BB*SEQ)/128), blk, 0, stream>>>(attn_out, Wo, out_attn);
}

// Round 7
// 2302.024 us; speedup vs baseline: 4.4045x; 4.4045x over previous
//
#include <hip/hip_runtime.h>
#include <hip/hip_bf16.h>

typedef __hip_bfloat16 bf16;

#define NH   16
#define HD   128
#define SEQ  2048
#define BB   2
#define HID  2048

// ln(10000)/64
#define ROPE_C 0.14391156856f

using frag  = __attribute__((ext_vector_type(8))) short;   // 8 bf16 = 4 VGPRs
using f32x4 = __attribute__((ext_vector_type(4))) float;

// ---------- helpers ----------

__device__ __forceinline__ void unpack8(const bf16* p, float* f) {
    uint4 u = *reinterpret_cast<const uint4*>(p);
    const unsigned* w = reinterpret_cast<const unsigned*>(&u);
#pragma unroll
    for (int i = 0; i < 4; ++i) {
        f[2*i]   = __uint_as_float(w[i] << 16);
        f[2*i+1] = __uint_as_float(w[i] & 0xffff0000u);
    }
}

__device__ __forceinline__ void stage16_bf16(const bf16* g, float* lds) {
    float tmp[8];
    unpack8(g, tmp);
    *reinterpret_cast<float4*>(lds)     = *reinterpret_cast<float4*>(&tmp[0]);
    *reinterpret_cast<float4*>(lds + 4) = *reinterpret_cast<float4*>(&tmp[4]);
    unpack8(g + 8, tmp);
    *reinterpret_cast<float4*>(lds + 8)  = *reinterpret_cast<float4*>(&tmp[0]);
    *reinterpret_cast<float4*>(lds + 12) = *reinterpret_cast<float4*>(&tmp[4]);
}

__device__ __forceinline__ void stage16_f32(const float* g, float* lds) {
    const float4* s = reinterpret_cast<const float4*>(g);
    float4* d = reinterpret_cast<float4*>(lds);
    d[0]=s[0]; d[1]=s[1]; d[2]=s[2]; d[3]=s[3];
}

// ---------- Q projection + fused RoPE (fp32 VALU GEMM) ----------
__global__ __launch_bounds__(256) void gemm_q_rope(const float* __restrict__ A,
                                                   const float* __restrict__ W,
                                                   bf16* __restrict__ C) {
    __shared__ float As[128][36];
    __shared__ float Bs[128][36];
    const int tid = threadIdx.x;
    const int tx = tid & 15, ty = tid >> 4;
    const int row0 = blockIdx.y * 128;
    const int col0 = blockIdx.x * 128;
    const int sr = tid >> 1;
    const int sc = (tid & 1) * 16;
    float acc[8][8] = {};
    for (int k0 = 0; k0 < HID; k0 += 32) {
        stage16_f32(A + (size_t)(row0 + sr) * HID + k0 + sc, &As[sr][sc]);
        stage16_f32(W + (size_t)(col0 + sr) * HID + k0 + sc, &Bs[sr][sc]);
        __syncthreads();
#pragma unroll
        for (int kk = 0; kk < 32; kk += 4) {
            float4 a[8], b[8];
#pragma unroll
            for (int i = 0; i < 8; ++i) a[i] = *reinterpret_cast<const float4*>(&As[ty + 16*i][kk]);
#pragma unroll
            for (int j = 0; j < 8; ++j) b[j] = *reinterpret_cast<const float4*>(&Bs[tx + 16*j][kk]);
#pragma unroll
            for (int i = 0; i < 8; ++i)
#pragma unroll
                for (int j = 0; j < 8; ++j)
                    acc[i][j] += a[i].x*b[j].x + a[i].y*b[j].y + a[i].z*b[j].z + a[i].w*b[j].w;
        }
        __syncthreads();
    }
#pragma unroll
    for (int i = 0; i < 8; ++i) {
        const int r = row0 + ty + 16*i;
        const int s = r & (SEQ - 1);
        bf16* crow = C + (size_t)r * HID + col0;
#pragma unroll
        for (int j = 0; j < 4; ++j) {
            const int d = tx + 16*j;
            const float invf = expf(-(float)d * ROPE_C);
            float sn, cs;
            sincosf((float)s * invf, &sn, &cs);
            const float x1 = acc[i][j], x2 = acc[i][j+4];
            crow[d]      = __float2bfloat16(x1*cs - x2*sn);
            crow[d + 64] = __float2bfloat16(x2*cs + x1*sn);
        }
    }
}

// ---------- K/V projection; K roped. fp32 outputs + bf16 mirrors (kb, vt^T) ----------
__global__ __launch_bounds__(256) void gemm_kv_rope(const float* __restrict__ A,
                                                    const float* __restrict__ Wk,
                                                    const float* __restrict__ Wv,
                                                    float* __restrict__ Ck,
                                                    float* __restrict__ Cv,
                                                    bf16* __restrict__ kb,
                                                    bf16* __restrict__ vt) {
    __shared__ float As[64][68];
    __shared__ float Bs[128][68];
    const int tid = threadIdx.x;
    const int tx = tid & 15, ty = tid >> 4;
    const int row0 = blockIdx.y * 64;
    const bool is_v = (blockIdx.x != 0);
    const float* W = is_v ? Wv : Wk;
    float* C       = is_v ? Cv : Ck;
    const int sr = tid >> 2;
    const int sc = (tid & 3) * 16;
    const int br = tid >> 1;
    const int bc = (tid & 1) * 16;
    float acc[4][8] = {};
    for (int k0 = 0; k0 < HID; k0 += 64) {
        stage16_f32(A + (size_t)(row0 + sr) * HID + k0 + sc, &As[sr][sc]);
        stage16_f32(W + (size_t)br * HID + k0 + bc,      &Bs[br][bc]);
        stage16_f32(W + (size_t)br * HID + k0 + bc + 32, &Bs[br][bc + 32]);
        __syncthreads();
#pragma unroll
        for (int kk = 0; kk < 64; kk += 4) {
            float4 a[4], b[8];
#pragma unroll
            for (int i = 0; i < 4; ++i) a[i] = *reinterpret_cast<const float4*>(&As[ty + 16*i][kk]);
#pragma unroll
            for (int j = 0; j < 8; ++j) b[j] = *reinterpret_cast<const float4*>(&Bs[tx + 16*j][kk]);
#pragma unroll
            for (int i = 0; i < 4; ++i)
#pragma unroll
                for (int j = 0; j < 8; ++j)
                    acc[i][j] += a[i].x*b[j].x + a[i].y*b[j].y + a[i].z*b[j].z + a[i].w*b[j].w;
        }
        __syncthreads();
    }
#pragma unroll
    for (int i = 0; i < 4; ++i) {
        const int r = row0 + ty + 16*i;       // b*SEQ + s
        const int s = r & (SEQ - 1);
        const int b = r >> 11;
        float* crow = C + (size_t)r * HD;
        if (is_v) {
#pragma unroll
            for (int j = 0; j < 8; ++j) {
                const int d = tx + 16*j;
                const float val = acc[i][j];
                crow[d] = val;
                vt[((size_t)b * HD + d) * SEQ + s] = __float2bfloat16(val);
            }
        } else {
#pragma unroll
            for (int j = 0; j < 4; ++j) {
                const int d = tx + 16*j;
                const float invf = expf(-(float)d * ROPE_C);
                float sn, cs;
                sincosf((float)s * invf, &sn, &cs);
                const float y1 = acc[i][j]*cs - acc[i][j+4]*sn;
                const float y2 = acc[i][j+4]*cs + acc[i][j]*sn;
                crow[d]      = y1;
                crow[d + 64] = y2;
                kb[(size_t)r * HD + d]      = __float2bfloat16(y1);
                kb[(size_t)r * HD + d + 64] = __float2bfloat16(y2);
            }
        }
    }
}

// ---------- flash MFMA attention ----------
// grid (SEQ/64, NH, B), 256 threads = 4 waves. Wave w owns q-rows q0+16w..+15.
// mfma_f32_16x16x32_bf16: A/B frag [idx=lane&15][k=quad*8+j]; D col=lane&15,
// row=quad*4+reg. First operand supplies D rows.
__global__ __launch_bounds__(256) void attn_mfma(const bf16* __restrict__ qbuf,
                                                 const bf16* __restrict__ kb,
                                                 const bf16* __restrict__ vt,
                                                 bf16* __restrict__ attn_out) {
    __shared__ bf16 Ks[64][136];   // keys x dims (row 272B, 16B-aligned)
    __shared__ bf16 Vt[128][72];   // dims x keys
    __shared__ bf16 Ps[64][72];    // 4 waves x 16 qrows x 64 keys (wave-private slabs)

    const int tid  = threadIdx.x;
    const int wave = tid >> 6;
    const int lane = tid & 63;
    const int quad = lane >> 4;
    const int l15  = lane & 15;
    const int q0   = blockIdx.x * 64;
    const int h    = blockIdx.y;
    const int b    = blockIdx.z;

    const bf16* kbb = kb + (size_t)b * SEQ * HD;
    const bf16* vtb = vt + (size_t)b * HD * SEQ;

    // Q fragments in registers (A-operand layout), scale NOT folded (folded into exp)
    frag qf[4];
    {
        const bf16* qrow = qbuf + ((size_t)(b * SEQ + q0 + wave * 16 + l15)) * HID + h * HD;
#pragma unroll
        for (int c = 0; c < 4; ++c)
            qf[c] = *reinterpret_cast<const frag*>(qrow + c * 32 + quad * 8);
    }

    f32x4 oacc[8];
#pragma unroll
    for (int dt = 0; dt < 8; ++dt) oacc[dt] = (f32x4){0.f, 0.f, 0.f, 0.f};
    float mrow[4] = {-1e30f, -1e30f, -1e30f, -1e30f};
    float lrow[4] = {0.f, 0.f, 0.f, 0.f};
    const float scale = 0.088388347648318433f;   // 1/sqrt(128)

    for (int t0 = 0; t0 < SEQ; t0 += 64) {
        __syncthreads();   // protect prior-tile LDS reads
        {   // stage K tile: 64 keys x 128 dims, coalesced
            const int r  = tid >> 2;
            const int c0 = (tid & 3) * 32;
            const uint4* src = reinterpret_cast<const uint4*>(kbb + (size_t)(t0 + r) * HD + c0);
            uint4* dst = reinterpret_cast<uint4*>(&Ks[r][c0]);
#pragma unroll
            for (int i = 0; i < 4; ++i) dst[i] = src[i];
        }
        {   // stage V^T tile: 128 dims x 64 keys, coalesced (vt is pre-transposed)
            const int d  = tid >> 1;
            const int c0 = (tid & 1) * 32;
            const uint4* src = reinterpret_cast<const uint4*>(vtb + (size_t)d * SEQ + t0 + c0);
            uint4* dst = reinterpret_cast<uint4*>(&Vt[d][c0]);
#pragma unroll
            for (int i = 0; i < 4; ++i) dst[i] = src[i];
        }
        __syncthreads();

        // S = Q K^T : 4 column tiles of 16 keys
        f32x4 s4[4];
#pragma unroll
        for (int t = 0; t < 4; ++t) {
            f32x4 acc = (f32x4){0.f, 0.f, 0.f, 0.f};
#pragma unroll
            for (int c = 0; c < 4; ++c) {
                frag kf = *reinterpret_cast<const frag*>(&Ks[t * 16 + l15][c * 32 + quad * 8]);
                acc = __builtin_amdgcn_mfma_f32_16x16x32_bf16(qf[c], kf, acc, 0, 0, 0);
            }
            s4[t] = acc;
        }

        // online softmax (raw-score max tracking, scale folded into exp)
        float al[4];
#pragma unroll
        for (int r = 0; r < 4; ++r) {
            float mx = fmaxf(fmaxf(s4[0][r], s4[1][r]), fmaxf(s4[2][r], s4[3][r]));
            mx = fmaxf(mx, __shfl_xor(mx, 1));
            mx = fmaxf(mx, __shfl_xor(mx, 2));
            mx = fmaxf(mx, __shfl_xor(mx, 4));
            mx = fmaxf(mx, __shfl_xor(mx, 8));
            const float mn = fmaxf(mrow[r], mx);
            al[r] = __expf((mrow[r] - mn) * scale);
            float ps = 0.f;
#pragma unroll
            for (int t = 0; t < 4; ++t) {
                const float p = __expf((s4[t][r] - mn) * scale);
                Ps[wave * 16 + quad * 4 + r][t * 16 + l15] = __float2bfloat16(p);
                ps += p;
            }
            ps += __shfl_xor(ps, 1);
            ps += __shfl_xor(ps, 2);
            ps += __shfl_xor(ps, 4);
            ps += __shfl_xor(ps, 8);
            lrow[r] = lrow[r] * al[r] + ps;
            mrow[r] = mn;
        }

        // rescale O accumulators
#pragma unroll
        for (int dt = 0; dt < 8; ++dt)
#pragma unroll
            for (int r = 0; r < 4; ++r) oacc[dt][r] *= al[r];

        // P back in A-operand layout (wave-private slab; intra-wave lgkmcnt only)
        frag pa0 = *reinterpret_cast<const frag*>(&Ps[wave * 16 + l15][quad * 8]);
        frag pa1 = *reinterpret_cast<const frag*>(&Ps[wave * 16 + l15][32 + quad * 8]);

        // O += P V  (V^T rows as B operand)
#pragma unroll
        for (int dt = 0; dt < 8; ++dt) {
            frag v0 = *reinterpret_cast<const frag*>(&Vt[dt * 16 + l15][quad * 8]);
            frag v1 = *reinterpret_cast<const frag*>(&Vt[dt * 16 + l15][32 + quad * 8]);
            oacc[dt] = __builtin_amdgcn_mfma_f32_16x16x32_bf16(pa0, v0, oacc[dt], 0, 0, 0);
            oacc[dt] = __builtin_amdgcn_mfma_f32_16x16x32_bf16(pa1, v1, oacc[dt], 0, 0, 0);
        }
    }

    // epilogue: rows q0+wave*16+quad*4+r, cols h*128 + dt*16 + l15
#pragma unroll
    for (int r = 0; r < 4; ++r) {
        const float inv = 1.f / lrow[r];
        const int s = q0 + wave * 16 + quad * 4 + r;
        bf16* orow = attn_out + ((size_t)(b * SEQ + s)) * HID + h * HD;
#pragma unroll
        for (int dt = 0; dt < 8; ++dt)
            orow[dt * 16 + l15] = __float2bfloat16(oacc[dt][r] * inv);
    }
}

// ---------- final projection: C(f32) = A(bf16) * Wo(f32)^T ----------
__global__ __launch_bounds__(256) void gemm_bf16A(const bf16* __restrict__ A,
                                                  const float* __restrict__ W,
                                                  float* __restrict__ C) {
    __shared__ float As[128][36];
    __shared__ float Bs[128][36];
    const int tid = threadIdx.x;
    const int tx = tid & 15, ty = tid >> 4;
    const int row0 = blockIdx.y * 128;
    const int col0 = blockIdx.x * 128;
    const int sr = tid >> 1;
    const int sc = (tid & 1) * 16;
    float acc[8][8] = {};
    for (int k0 = 0; k0 < HID; k0 += 32) {
        stage16_bf16(A + (size_t)(row0 + sr) * HID + k0 + sc, &As[sr][sc]);
        stage16_f32 (W + (size_t)(col0 + sr) * HID + k0 + sc, &Bs[sr][sc]);
        __syncthreads();
#pragma unroll
        for (int kk = 0; kk < 32; kk += 4) {
            float4 a[8], b[8];
#pragma unroll
            for (int i = 0; i < 8; ++i) a[i] = *reinterpret_cast<const float4*>(&As[ty + 16*i][kk]);
#pragma unroll
            for (int j = 0; j < 8; ++j) b[j] = *reinterpret_cast<const float4*>(&Bs[tx + 16*j][kk]);
#pragma unroll
            for (int i = 0; i < 8; ++i)
#pragma unroll
                for (int j = 0; j < 8; ++j)
                    acc[i][j] += a[i].x*b[j].x + a[i].y*b[j].y + a[i].z*b[j].z + a[i].w*b[j].w;
        }
        __syncthreads();
    }
#pragma unroll
    for (int i = 0; i < 8; ++i) {
        const size_t r = row0 + ty + 16*i;
#pragma unroll
        for (int j = 0; j < 8; ++j)
            C[r * HID + col0 + tx + 16*j] = acc[i][j];
    }
}

// ---------- launch ----------
extern "C" void kernel_launch(void* const* d_in, const int* in_sizes, int n_in,
                              void* d_out, int out_size, void* d_ws, size_t ws_size,
                              hipStream_t stream) {
    const float* hs = (const float*)d_in[0];
    const float* Wq = (const float*)d_in[1];
    const float* Wk = (const float*)d_in[2];
    const float* Wv = (const float*)d_in[3];
    const float* Wo = (const float*)d_in[4];

    float* out      = (float*)d_out;
    float* out_attn = out;                         // [B,S,H]    8388608 f32 (33.55 MB)
    float* out_k    = out + 8388608;               // [B,1,S,HD]  524288 f32
    float* out_v    = out + 8388608 + 524288;      // [B,1,S,HD]  524288 f32

    // Scratch inside d_out's attn region (all consumed before gemm_bf16A writes it):
    //   bytes 0        .. 16777216 : qbuf  (bf16 roped q, [B,S,H])
    //   bytes 16777216 .. 17825792 : kb    (bf16 roped k, [B,S,128])
    //   bytes 17825792 .. 18874368 : vt    (bf16 v^T,     [B,128,S])
    bf16* qbuf = (bf16*)d_out;
    bf16* kb   = (bf16*)((char*)d_out + 16777216);
    bf16* vt   = (bf16*)((char*)d_out + 17825792);
    bf16* attn_out = (bf16*)d_ws;                  // [B,S,H] bf16, 16.78 MB

    dim3 blk(256);
    gemm_q_rope <<<dim3(HID/128, (BB*SEQ)/128), blk, 0, stream>>>(hs, Wq, qbuf);
    gemm_kv_rope<<<dim3(2,       (BB*SEQ)/64 ), blk, 0, stream>>>(hs, Wk, Wv, out_k, out_v, kb, vt);
    attn_mfma   <<<dim3(SEQ/64, NH, BB),        blk, 0, stream>>>(qbuf, kb, vt, attn_out);
    gemm_bf16A  <<<dim3(HID/128, (BB*SEQ)/128), blk, 0, stream>>>(attn_out, Wo, out_attn);
}

// Round 8
// 594.909 us; speedup vs baseline: 17.0435x; 3.8695x over previous
//
#include <hip/hip_runtime.h>
#include <hip/hip_bf16.h>

typedef __hip_bfloat16 bf16;

#define NH   16
#define HD   128
#define SEQ  2048
#define BB   2
#define HID  2048

// ln(10000)/64
#define ROPE_C 0.14391156856f

using frag  = __attribute__((ext_vector_type(8))) short;   // 8 bf16 = 4 VGPRs
using f32x4 = __attribute__((ext_vector_type(4))) float;

// ---------- helpers ----------

// pack 8 fp32 -> 8 bf16 (one 16B LDS write)
__device__ __forceinline__ void cvt8_store(const float4 f0, const float4 f1, bf16* dst) {
    union { frag v; bf16 h[8]; } p;
    p.h[0] = __float2bfloat16(f0.x); p.h[1] = __float2bfloat16(f0.y);
    p.h[2] = __float2bfloat16(f0.z); p.h[3] = __float2bfloat16(f0.w);
    p.h[4] = __float2bfloat16(f1.x); p.h[5] = __float2bfloat16(f1.y);
    p.h[6] = __float2bfloat16(f1.z); p.h[7] = __float2bfloat16(f1.w);
    *reinterpret_cast<frag*>(dst) = p.v;
}

// stage 16 fp32 -> 16 bf16 into LDS (row-chunk)
__device__ __forceinline__ void stage16_cvt(const float* g, bf16* lds) {
    const float4* s = reinterpret_cast<const float4*>(g);
    float4 f0 = s[0], f1 = s[1], f2 = s[2], f3 = s[3];
    cvt8_store(f0, f1, lds);
    cvt8_store(f2, f3, lds + 8);
}

// ---------- MFMA GEMM core macro-parts ----------
// Tile BM=128 x BN=128 x BK=32; 4 waves, wave owns 32 rows x 128 cols.
// A/B frag layout [idx=lane&15][k=quad*8..+7]; D: col=lane&15, row=quad*4+reg.
// LDS rows padded to 40 bf16 (80B): frag b128 reads conflict-free.

// ---------- Q projection + fused RoPE (MFMA) ----------
__global__ __launch_bounds__(256) void gemm_q_mfma(const float* __restrict__ A,
                                                   const float* __restrict__ W,
                                                   bf16* __restrict__ C) {
    __shared__ bf16 Asl[128][40];
    __shared__ bf16 Bsl[128][40];
    const int tid  = threadIdx.x;
    const int wave = tid >> 6;
    const int lane = tid & 63;
    const int quad = lane >> 4;
    const int l15  = lane & 15;
    const int row0 = blockIdx.y * 128;
    const int col0 = blockIdx.x * 128;   // = h*128
    const int sr = tid >> 1;             // 0..127
    const int sc = (tid & 1) * 16;       // 0 or 16

    f32x4 acc[2][8];
#pragma unroll
    for (int i = 0; i < 2; ++i)
#pragma unroll
        for (int j = 0; j < 8; ++j) acc[i][j] = (f32x4){0.f,0.f,0.f,0.f};

    for (int k0 = 0; k0 < HID; k0 += 32) {
        __syncthreads();
        stage16_cvt(A + (size_t)(row0 + sr) * HID + k0 + sc, &Asl[sr][sc]);
        stage16_cvt(W + (size_t)(col0 + sr) * HID + k0 + sc, &Bsl[sr][sc]);
        __syncthreads();
        frag af[2], bfr[8];
#pragma unroll
        for (int i = 0; i < 2; ++i)
            af[i] = *reinterpret_cast<const frag*>(&Asl[wave*32 + 16*i + l15][quad*8]);
#pragma unroll
        for (int j = 0; j < 8; ++j)
            bfr[j] = *reinterpret_cast<const frag*>(&Bsl[16*j + l15][quad*8]);
#pragma unroll
        for (int i = 0; i < 2; ++i)
#pragma unroll
            for (int j = 0; j < 8; ++j)
                acc[i][j] = __builtin_amdgcn_mfma_f32_16x16x32_bf16(af[i], bfr[j], acc[i][j], 0, 0, 0);
    }

    // epilogue: rope pairs (d, d+64) = col tiles (j, j+4), same thread
#pragma unroll
    for (int i = 0; i < 2; ++i)
#pragma unroll
        for (int r = 0; r < 4; ++r) {
            const int row = row0 + wave*32 + 16*i + quad*4 + r;
            const int s = row & (SEQ - 1);
            bf16* crow = C + (size_t)row * HID + col0;
#pragma unroll
            for (int j = 0; j < 4; ++j) {
                const int d = 16*j + l15;
                const float invf = expf(-(float)d * ROPE_C);
                float sn, cs;
                sincosf((float)s * invf, &sn, &cs);
                const float x1 = acc[i][j][r], x2 = acc[i][j+4][r];
                crow[d]      = __float2bfloat16(x1*cs - x2*sn);
                crow[d + 64] = __float2bfloat16(x2*cs + x1*sn);
            }
        }
}

// ---------- K/V projection (MFMA); K roped; fp32 outs + bf16 mirrors ----------
// grid (2, M/128): x==0 -> K, x==1 -> V.
__global__ __launch_bounds__(256) void gemm_kv_mfma(const float* __restrict__ A,
                                                    const float* __restrict__ Wk,
                                                    const float* __restrict__ Wv,
                                                    float* __restrict__ Ck,
                                                    float* __restrict__ Cv,
                                                    bf16* __restrict__ kb,
                                                    bf16* __restrict__ vt) {
    __shared__ bf16 Asl[128][40];
    __shared__ bf16 Bsl[128][40];
    const int tid  = threadIdx.x;
    const int wave = tid >> 6;
    const int lane = tid & 63;
    const int quad = lane >> 4;
    const int l15  = lane & 15;
    const int row0 = blockIdx.y * 128;
    const bool is_v = (blockIdx.x != 0);
    const float* W = is_v ? Wv : Wk;
    const int sr = tid >> 1;
    const int sc = (tid & 1) * 16;

    f32x4 acc[2][8];
#pragma unroll
    for (int i = 0; i < 2; ++i)
#pragma unroll
        for (int j = 0; j < 8; ++j) acc[i][j] = (f32x4){0.f,0.f,0.f,0.f};

    for (int k0 = 0; k0 < HID; k0 += 32) {
        __syncthreads();
        stage16_cvt(A + (size_t)(row0 + sr) * HID + k0 + sc, &Asl[sr][sc]);
        stage16_cvt(W + (size_t)sr * HID + k0 + sc, &Bsl[sr][sc]);
        __syncthreads();
        frag af[2], bfr[8];
#pragma unroll
        for (int i = 0; i < 2; ++i)
            af[i] = *reinterpret_cast<const frag*>(&Asl[wave*32 + 16*i + l15][quad*8]);
#pragma unroll
        for (int j = 0; j < 8; ++j)
            bfr[j] = *reinterpret_cast<const frag*>(&Bsl[16*j + l15][quad*8]);
#pragma unroll
        for (int i = 0; i < 2; ++i)
#pragma unroll
            for (int j = 0; j < 8; ++j)
                acc[i][j] = __builtin_amdgcn_mfma_f32_16x16x32_bf16(af[i], bfr[j], acc[i][j], 0, 0, 0);
    }

#pragma unroll
    for (int i = 0; i < 2; ++i)
#pragma unroll
        for (int r = 0; r < 4; ++r) {
            const int row = row0 + wave*32 + 16*i + quad*4 + r;   // b*SEQ + s
            const int s = row & (SEQ - 1);
            const int b = row >> 11;
            if (is_v) {
                float* crow = Cv + (size_t)row * HD;
#pragma unroll
                for (int j = 0; j < 8; ++j) {
                    const int d = 16*j + l15;
                    const float val = acc[i][j][r];
                    crow[d] = val;
                    vt[((size_t)b * HD + d) * SEQ + s] = __float2bfloat16(val);
                }
            } else {
                float* crow = Ck + (size_t)row * HD;
#pragma unroll
                for (int j = 0; j < 4; ++j) {
                    const int d = 16*j + l15;
                    const float invf = expf(-(float)d * ROPE_C);
                    float sn, cs;
                    sincosf((float)s * invf, &sn, &cs);
                    const float y1 = acc[i][j][r]*cs - acc[i][j+4][r]*sn;
                    const float y2 = acc[i][j+4][r]*cs + acc[i][j][r]*sn;
                    crow[d]      = y1;
                    crow[d + 64] = y2;
                    kb[(size_t)row * HD + d]      = __float2bfloat16(y1);
                    kb[(size_t)row * HD + d + 64] = __float2bfloat16(y2);
                }
            }
        }
}

// ---------- flash MFMA attention (unchanged from round 7) ----------
__global__ __launch_bounds__(256) void attn_mfma(const bf16* __restrict__ qbuf,
                                                 const bf16* __restrict__ kb,
                                                 const bf16* __restrict__ vt,
                                                 bf16* __restrict__ attn_out) {
    __shared__ bf16 Ks[64][136];
    __shared__ bf16 Vt[128][72];
    __shared__ bf16 Ps[64][72];

    const int tid  = threadIdx.x;
    const int wave = tid >> 6;
    const int lane = tid & 63;
    const int quad = lane >> 4;
    const int l15  = lane & 15;
    const int q0   = blockIdx.x * 64;
    const int h    = blockIdx.y;
    const int b    = blockIdx.z;

    const bf16* kbb = kb + (size_t)b * SEQ * HD;
    const bf16* vtb = vt + (size_t)b * HD * SEQ;

    frag qf[4];
    {
        const bf16* qrow = qbuf + ((size_t)(b * SEQ + q0 + wave * 16 + l15)) * HID + h * HD;
#pragma unroll
        for (int c = 0; c < 4; ++c)
            qf[c] = *reinterpret_cast<const frag*>(qrow + c * 32 + quad * 8);
    }

    f32x4 oacc[8];
#pragma unroll
    for (int dt = 0; dt < 8; ++dt) oacc[dt] = (f32x4){0.f, 0.f, 0.f, 0.f};
    float mrow[4] = {-1e30f, -1e30f, -1e30f, -1e30f};
    float lrow[4] = {0.f, 0.f, 0.f, 0.f};
    const float scale = 0.088388347648318433f;   // 1/sqrt(128)

    for (int t0 = 0; t0 < SEQ; t0 += 64) {
        __syncthreads();
        {
            const int r  = tid >> 2;
            const int c0 = (tid & 3) * 32;
            const uint4* src = reinterpret_cast<const uint4*>(kbb + (size_t)(t0 + r) * HD + c0);
            uint4* dst = reinterpret_cast<uint4*>(&Ks[r][c0]);
#pragma unroll
            for (int i = 0; i < 4; ++i) dst[i] = src[i];
        }
        {
            const int d  = tid >> 1;
            const int c0 = (tid & 1) * 32;
            const uint4* src = reinterpret_cast<const uint4*>(vtb + (size_t)d * SEQ + t0 + c0);
            uint4* dst = reinterpret_cast<uint4*>(&Vt[d][c0]);
#pragma unroll
            for (int i = 0; i < 4; ++i) dst[i] = src[i];
        }
        __syncthreads();

        f32x4 s4[4];
#pragma unroll
        for (int t = 0; t < 4; ++t) {
            f32x4 acc = (f32x4){0.f, 0.f, 0.f, 0.f};
#pragma unroll
            for (int c = 0; c < 4; ++c) {
                frag kf = *reinterpret_cast<const frag*>(&Ks[t * 16 + l15][c * 32 + quad * 8]);
                acc = __builtin_amdgcn_mfma_f32_16x16x32_bf16(qf[c], kf, acc, 0, 0, 0);
            }
            s4[t] = acc;
        }

        float al[4];
#pragma unroll
        for (int r = 0; r < 4; ++r) {
            float mx = fmaxf(fmaxf(s4[0][r], s4[1][r]), fmaxf(s4[2][r], s4[3][r]));
            mx = fmaxf(mx, __shfl_xor(mx, 1));
            mx = fmaxf(mx, __shfl_xor(mx, 2));
            mx = fmaxf(mx, __shfl_xor(mx, 4));
            mx = fmaxf(mx, __shfl_xor(mx, 8));
            const float mn = fmaxf(mrow[r], mx);
            al[r] = __expf((mrow[r] - mn) * scale);
            float ps = 0.f;
#pragma unroll
            for (int t = 0; t < 4; ++t) {
                const float p = __expf((s4[t][r] - mn) * scale);
                Ps[wave * 16 + quad * 4 + r][t * 16 + l15] = __float2bfloat16(p);
                ps += p;
            }
            ps += __shfl_xor(ps, 1);
            ps += __shfl_xor(ps, 2);
            ps += __shfl_xor(ps, 4);
            ps += __shfl_xor(ps, 8);
            lrow[r] = lrow[r] * al[r] + ps;
            mrow[r] = mn;
        }

#pragma unroll
        for (int dt = 0; dt < 8; ++dt)
#pragma unroll
            for (int r = 0; r < 4; ++r) oacc[dt][r] *= al[r];

        frag pa0 = *reinterpret_cast<const frag*>(&Ps[wave * 16 + l15][quad * 8]);
        frag pa1 = *reinterpret_cast<const frag*>(&Ps[wave * 16 + l15][32 + quad * 8]);

#pragma unroll
        for (int dt = 0; dt < 8; ++dt) {
            frag v0 = *reinterpret_cast<const frag*>(&Vt[dt * 16 + l15][quad * 8]);
            frag v1 = *reinterpret_cast<const frag*>(&Vt[dt * 16 + l15][32 + quad * 8]);
            oacc[dt] = __builtin_amdgcn_mfma_f32_16x16x32_bf16(pa0, v0, oacc[dt], 0, 0, 0);
            oacc[dt] = __builtin_amdgcn_mfma_f32_16x16x32_bf16(pa1, v1, oacc[dt], 0, 0, 0);
        }
    }

#pragma unroll
    for (int r = 0; r < 4; ++r) {
        const float inv = 1.f / lrow[r];
        const int s = q0 + wave * 16 + quad * 4 + r;
        bf16* orow = attn_out + ((size_t)(b * SEQ + s)) * HID + h * HD;
#pragma unroll
        for (int dt = 0; dt < 8; ++dt)
            orow[dt * 16 + l15] = __float2bfloat16(oacc[dt][r] * inv);
    }
}

// ---------- final projection (MFMA): C(f32) = A(bf16) * Wo(f32)^T ----------
__global__ __launch_bounds__(256) void gemm_o_mfma(const bf16* __restrict__ A,
                                                   const float* __restrict__ W,
                                                   float* __restrict__ C) {
    __shared__ bf16 Asl[128][40];
    __shared__ bf16 Bsl[128][40];
    const int tid  = threadIdx.x;
    const int wave = tid >> 6;
    const int lane = tid & 63;
    const int quad = lane >> 4;
    const int l15  = lane & 15;
    const int row0 = blockIdx.y * 128;
    const int col0 = blockIdx.x * 128;
    const int sr = tid >> 1;
    const int sc = (tid & 1) * 16;

    f32x4 acc[2][8];
#pragma unroll
    for (int i = 0; i < 2; ++i)
#pragma unroll
        for (int j = 0; j < 8; ++j) acc[i][j] = (f32x4){0.f,0.f,0.f,0.f};

    for (int k0 = 0; k0 < HID; k0 += 32) {
        __syncthreads();
        {   // A already bf16: straight 16B copies
            const bf16* ap = A + (size_t)(row0 + sr) * HID + k0 + sc;
            uint4 u0 = *reinterpret_cast<const uint4*>(ap);
            uint4 u1 = *reinterpret_cast<const uint4*>(ap + 8);
            *reinterpret_cast<uint4*>(&Asl[sr][sc])     = u0;
            *reinterpret_cast<uint4*>(&Asl[sr][sc + 8]) = u1;
        }
        stage16_cvt(W + (size_t)(col0 + sr) * HID + k0 + sc, &Bsl[sr][sc]);
        __syncthreads();
        frag af[2], bfr[8];
#pragma unroll
        for (int i = 0; i < 2; ++i)
            af[i] = *reinterpret_cast<const frag*>(&Asl[wave*32 + 16*i + l15][quad*8]);
#pragma unroll
        for (int j = 0; j < 8; ++j)
            bfr[j] = *reinterpret_cast<const frag*>(&Bsl[16*j + l15][quad*8]);
#pragma unroll
        for (int i = 0; i < 2; ++i)
#pragma unroll
            for (int j = 0; j < 8; ++j)
                acc[i][j] = __builtin_amdgcn_mfma_f32_16x16x32_bf16(af[i], bfr[j], acc[i][j], 0, 0, 0);
    }

#pragma unroll
    for (int i = 0; i < 2; ++i)
#pragma unroll
        for (int r = 0; r < 4; ++r) {
            const int row = row0 + wave*32 + 16*i + quad*4 + r;
            float* crow = C + (size_t)row * HID + col0;
#pragma unroll
            for (int j = 0; j < 8; ++j)
                crow[16*j + l15] = acc[i][j][r];
        }
}

// ---------- launch ----------
extern "C" void kernel_launch(void* const* d_in, const int* in_sizes, int n_in,
                              void* d_out, int out_size, void* d_ws, size_t ws_size,
                              hipStream_t stream) {
    const float* hs = (const float*)d_in[0];
    const float* Wq = (const float*)d_in[1];
    const float* Wk = (const float*)d_in[2];
    const float* Wv = (const float*)d_in[3];
    const float* Wo = (const float*)d_in[4];

    float* out      = (float*)d_out;
    float* out_attn = out;                         // [B,S,H]    8388608 f32 (33.55 MB)
    float* out_k    = out + 8388608;               // [B,1,S,HD]  524288 f32
    float* out_v    = out + 8388608 + 524288;      // [B,1,S,HD]  524288 f32

    // Scratch inside d_out's attn region (consumed before gemm_o_mfma writes it):
    bf16* qbuf = (bf16*)d_out;                     // bytes 0..16.78M  roped q bf16
    bf16* kb   = (bf16*)((char*)d_out + 16777216); // bytes ..17.83M   roped k bf16
    bf16* vt   = (bf16*)((char*)d_out + 17825792); // bytes ..18.87M   v^T bf16
    bf16* attn_out = (bf16*)d_ws;                  // [B,S,H] bf16, 16.78 MB

    dim3 blk(256);
    gemm_q_mfma <<<dim3(HID/128, (BB*SEQ)/128), blk, 0, stream>>>(hs, Wq, qbuf);
    gemm_kv_mfma<<<dim3(2,       (BB*SEQ)/128), blk, 0, stream>>>(hs, Wk, Wv, out_k, out_v, kb, vt);
    attn_mfma   <<<dim3(SEQ/64, NH, BB),        blk, 0, stream>>>(qbuf, kb, vt, attn_out);
    gemm_o_mfma <<<dim3(HID/128, (BB*SEQ)/128), blk, 0, stream>>>(attn_out, Wo, out_attn);
}

// Round 9
// 537.878 us; speedup vs baseline: 18.8506x; 1.1060x over previous
//
#include <hip/hip_runtime.h>
#include <hip/hip_bf16.h>

typedef __hip_bfloat16 bf16;

#define NH   16
#define HD   128
#define SEQ  2048
#define BB   2
#define HID  2048

// ln(10000)/64
#define ROPE_C 0.14391156856f

using frag  = __attribute__((ext_vector_type(8))) short;   // 8 bf16 = 4 VGPRs
using f32x4 = __attribute__((ext_vector_type(4))) float;

// ---------- helpers ----------

// pack 8 fp32 -> 8 bf16 (one 16B LDS write)
__device__ __forceinline__ void cvt8_store(const float4 f0, const float4 f1, bf16* dst) {
    union { frag v; bf16 h[8]; } p;
    p.h[0] = __float2bfloat16(f0.x); p.h[1] = __float2bfloat16(f0.y);
    p.h[2] = __float2bfloat16(f0.z); p.h[3] = __float2bfloat16(f0.w);
    p.h[4] = __float2bfloat16(f1.x); p.h[5] = __float2bfloat16(f1.y);
    p.h[6] = __float2bfloat16(f1.z); p.h[7] = __float2bfloat16(f1.w);
    *reinterpret_cast<frag*>(dst) = p.v;
}

// ---------- MFMA GEMM, chunk-contiguous LDS ----------
// Tile BM=128 x BN=128 x BK=32; 4 waves, wave owns 32 rows x 128 cols.
// LDS chunk id n = (m16*16 + l15)*4 + quad  (m16 = row>>4), chunk at n*8 bf16.
// Frag reads are 64-lane-contiguous 16B -> conflict-free; staging writes are
// lane-contiguous -> conflict-free; global staging reads 128B-coalesced.

// ---------- Q projection + fused RoPE (MFMA) ----------
__global__ __launch_bounds__(256) void gemm_q_mfma(const float* __restrict__ A,
                                                   const float* __restrict__ W,
                                                   bf16* __restrict__ C) {
    __shared__ bf16 Asl[4096];
    __shared__ bf16 Bsl[4096];
    const int tid  = threadIdx.x;
    const int wave = tid >> 6;
    const int lane = tid & 63;
    const int quad = lane >> 4;
    const int l15  = lane & 15;
    const int row0 = blockIdx.y * 128;
    const int col0 = blockIdx.x * 128;   // = h*128

    // staging chunk decode (2 chunks/thread)
    const int n0 = tid, n1 = tid + 256;
    const int r0 = ((n0 >> 2) & 15) + ((n0 >> 6) << 4), c0 = (n0 & 3) * 8;
    const int r1 = ((n1 >> 2) & 15) + ((n1 >> 6) << 4), c1 = (n1 & 3) * 8;

    f32x4 acc[2][8];
#pragma unroll
    for (int i = 0; i < 2; ++i)
#pragma unroll
        for (int j = 0; j < 8; ++j) acc[i][j] = (f32x4){0.f,0.f,0.f,0.f};

    for (int k0 = 0; k0 < HID; k0 += 32) {
        __syncthreads();
        {
            const float4* a0 = reinterpret_cast<const float4*>(A + (size_t)(row0 + r0) * HID + k0 + c0);
            const float4* a1 = reinterpret_cast<const float4*>(A + (size_t)(row0 + r1) * HID + k0 + c1);
            const float4* b0 = reinterpret_cast<const float4*>(W + (size_t)(col0 + r0) * HID + k0 + c0);
            const float4* b1 = reinterpret_cast<const float4*>(W + (size_t)(col0 + r1) * HID + k0 + c1);
            cvt8_store(a0[0], a0[1], &Asl[n0 * 8]);
            cvt8_store(a1[0], a1[1], &Asl[n1 * 8]);
            cvt8_store(b0[0], b0[1], &Bsl[n0 * 8]);
            cvt8_store(b1[0], b1[1], &Bsl[n1 * 8]);
        }
        __syncthreads();
        frag af[2], bfr[8];
#pragma unroll
        for (int i = 0; i < 2; ++i)
            af[i] = *reinterpret_cast<const frag*>(&Asl[((((wave*2+i)*16 + l15)*4) + quad) * 8]);
#pragma unroll
        for (int j = 0; j < 8; ++j)
            bfr[j] = *reinterpret_cast<const frag*>(&Bsl[(((j*16 + l15)*4) + quad) * 8]);
#pragma unroll
        for (int i = 0; i < 2; ++i)
#pragma unroll
            for (int j = 0; j < 8; ++j)
                acc[i][j] = __builtin_amdgcn_mfma_f32_16x16x32_bf16(af[i], bfr[j], acc[i][j], 0, 0, 0);
    }

    // epilogue: rope pairs (d, d+64) = col tiles (j, j+4), same thread
#pragma unroll
    for (int i = 0; i < 2; ++i)
#pragma unroll
        for (int r = 0; r < 4; ++r) {
            const int row = row0 + wave*32 + 16*i + quad*4 + r;
            const int s = row & (SEQ - 1);
            bf16* crow = C + (size_t)row * HID + col0;
#pragma unroll
            for (int j = 0; j < 4; ++j) {
                const int d = 16*j + l15;
                const float invf = expf(-(float)d * ROPE_C);
                float sn, cs;
                sincosf((float)s * invf, &sn, &cs);
                const float x1 = acc[i][j][r], x2 = acc[i][j+4][r];
                crow[d]      = __float2bfloat16(x1*cs - x2*sn);
                crow[d + 64] = __float2bfloat16(x2*cs + x1*sn);
            }
        }
}

// ---------- K/V projection (MFMA); K roped; fp32 outs + bf16 mirrors ----------
__global__ __launch_bounds__(256) void gemm_kv_mfma(const float* __restrict__ A,
                                                    const float* __restrict__ Wk,
                                                    const float* __restrict__ Wv,
                                                    float* __restrict__ Ck,
                                                    float* __restrict__ Cv,
                                                    bf16* __restrict__ kb,
                                                    bf16* __restrict__ vt) {
    __shared__ bf16 Asl[4096];
    __shared__ bf16 Bsl[4096];
    const int tid  = threadIdx.x;
    const int wave = tid >> 6;
    const int lane = tid & 63;
    const int quad = lane >> 4;
    const int l15  = lane & 15;
    const int row0 = blockIdx.y * 128;
    const bool is_v = (blockIdx.x != 0);
    const float* W = is_v ? Wv : Wk;

    const int n0 = tid, n1 = tid + 256;
    const int r0 = ((n0 >> 2) & 15) + ((n0 >> 6) << 4), c0 = (n0 & 3) * 8;
    const int r1 = ((n1 >> 2) & 15) + ((n1 >> 6) << 4), c1 = (n1 & 3) * 8;

    f32x4 acc[2][8];
#pragma unroll
    for (int i = 0; i < 2; ++i)
#pragma unroll
        for (int j = 0; j < 8; ++j) acc[i][j] = (f32x4){0.f,0.f,0.f,0.f};

    for (int k0 = 0; k0 < HID; k0 += 32) {
        __syncthreads();
        {
            const float4* a0 = reinterpret_cast<const float4*>(A + (size_t)(row0 + r0) * HID + k0 + c0);
            const float4* a1 = reinterpret_cast<const float4*>(A + (size_t)(row0 + r1) * HID + k0 + c1);
            const float4* b0 = reinterpret_cast<const float4*>(W + (size_t)r0 * HID + k0 + c0);
            const float4* b1 = reinterpret_cast<const float4*>(W + (size_t)r1 * HID + k0 + c1);
            cvt8_store(a0[0], a0[1], &Asl[n0 * 8]);
            cvt8_store(a1[0], a1[1], &Asl[n1 * 8]);
            cvt8_store(b0[0], b0[1], &Bsl[n0 * 8]);
            cvt8_store(b1[0], b1[1], &Bsl[n1 * 8]);
        }
        __syncthreads();
        frag af[2], bfr[8];
#pragma unroll
        for (int i = 0; i < 2; ++i)
            af[i] = *reinterpret_cast<const frag*>(&Asl[((((wave*2+i)*16 + l15)*4) + quad) * 8]);
#pragma unroll
        for (int j = 0; j < 8; ++j)
            bfr[j] = *reinterpret_cast<const frag*>(&Bsl[(((j*16 + l15)*4) + quad) * 8]);
#pragma unroll
        for (int i = 0; i < 2; ++i)
#pragma unroll
            for (int j = 0; j < 8; ++j)
                acc[i][j] = __builtin_amdgcn_mfma_f32_16x16x32_bf16(af[i], bfr[j], acc[i][j], 0, 0, 0);
    }

#pragma unroll
    for (int i = 0; i < 2; ++i)
#pragma unroll
        for (int r = 0; r < 4; ++r) {
            const int row = row0 + wave*32 + 16*i + quad*4 + r;   // b*SEQ + s
            const int s = row & (SEQ - 1);
            const int b = row >> 11;
            if (is_v) {
                float* crow = Cv + (size_t)row * HD;
#pragma unroll
                for (int j = 0; j < 8; ++j) {
                    const int d = 16*j + l15;
                    const float val = acc[i][j][r];
                    crow[d] = val;
                    vt[((size_t)b * HD + d) * SEQ + s] = __float2bfloat16(val);
                }
            } else {
                float* crow = Ck + (size_t)row * HD;
#pragma unroll
                for (int j = 0; j < 4; ++j) {
                    const int d = 16*j + l15;
                    const float invf = expf(-(float)d * ROPE_C);
                    float sn, cs;
                    sincosf((float)s * invf, &sn, &cs);
                    const float y1 = acc[i][j][r]*cs - acc[i][j+4][r]*sn;
                    const float y2 = acc[i][j+4][r]*cs + acc[i][j][r]*sn;
                    crow[d]      = y1;
                    crow[d + 64] = y2;
                    kb[(size_t)row * HD + d]      = __float2bfloat16(y1);
                    kb[(size_t)row * HD + d + 64] = __float2bfloat16(y2);
                }
            }
        }
}

// ---------- flash MFMA attention, chunk-contiguous LDS ----------
// Ks chunk n = ((c*4+t)*16+l15)*4+quad  (c=dim32-chunk, t=key16-tile)
// Vt chunk n = ((dt*2+h)*16+l15)*4+quad (dt=dim16-tile, h=key32-half)
// Ps per-wave chunk = (h*16+qrow)*4+quad' (qrow 0..15, key = h*32+quad'*8+j)
__global__ __launch_bounds__(256) void attn_mfma(const bf16* __restrict__ qbuf,
                                                 const bf16* __restrict__ kb,
                                                 const bf16* __restrict__ vt,
                                                 bf16* __restrict__ attn_out) {
    __shared__ bf16 Ks[8192];
    __shared__ bf16 Vt[8192];
    __shared__ bf16 Ps[4096];

    const int tid  = threadIdx.x;
    const int wave = tid >> 6;
    const int lane = tid & 63;
    const int quad = lane >> 4;
    const int l15  = lane & 15;
    const int q0   = blockIdx.x * 64;
    const int h    = blockIdx.y;
    const int b    = blockIdx.z;

    const bf16* kbb = kb + (size_t)b * SEQ * HD;
    const bf16* vtb = vt + (size_t)b * HD * SEQ;

    frag qf[4];
    {
        const bf16* qrow = qbuf + ((size_t)(b * SEQ + q0 + wave * 16 + l15)) * HID + h * HD;
#pragma unroll
        for (int c = 0; c < 4; ++c)
            qf[c] = *reinterpret_cast<const frag*>(qrow + c * 32 + quad * 8);
    }

    // staging chunk decodes (4 chunks/thread each for K and V)
    int kkey[4], kdim[4], vdim[4], vkey[4];
#pragma unroll
    for (int i = 0; i < 4; ++i) {
        const int n = tid + i * 256;
        kkey[i] = ((n >> 2) & 15) + (((n >> 6) & 3) << 4);
        kdim[i] = ((n >> 8) << 5) + ((n & 3) << 3);
        vdim[i] = ((n >> 2) & 15) + ((n >> 7) << 4);
        vkey[i] = (((n >> 6) & 1) << 5) + ((n & 3) << 3);
    }

    f32x4 oacc[8];
#pragma unroll
    for (int dt = 0; dt < 8; ++dt) oacc[dt] = (f32x4){0.f, 0.f, 0.f, 0.f};
    float mrow[4] = {-1e30f, -1e30f, -1e30f, -1e30f};
    float lrow[4] = {0.f, 0.f, 0.f, 0.f};
    const float scale = 0.088388347648318433f;   // 1/sqrt(128)

    for (int t0 = 0; t0 < SEQ; t0 += 64) {
        __syncthreads();
#pragma unroll
        for (int i = 0; i < 4; ++i) {
            const int n = tid + i * 256;
            *reinterpret_cast<uint4*>(&Ks[n * 8]) =
                *reinterpret_cast<const uint4*>(kbb + (size_t)(t0 + kkey[i]) * HD + kdim[i]);
            *reinterpret_cast<uint4*>(&Vt[n * 8]) =
                *reinterpret_cast<const uint4*>(vtb + (size_t)vdim[i] * SEQ + t0 + vkey[i]);
        }
        __syncthreads();

        // S = Q K^T : 4 column tiles of 16 keys
        f32x4 s4[4];
#pragma unroll
        for (int t = 0; t < 4; ++t) {
            f32x4 acc = (f32x4){0.f, 0.f, 0.f, 0.f};
#pragma unroll
            for (int c = 0; c < 4; ++c) {
                frag kf = *reinterpret_cast<const frag*>(&Ks[((((c*4+t)*16 + l15)*4) + quad) * 8]);
                acc = __builtin_amdgcn_mfma_f32_16x16x32_bf16(qf[c], kf, acc, 0, 0, 0);
            }
            s4[t] = acc;
        }

        // online softmax (rows quad*4+r; reduce over 16 l15-lanes)
        float al[4];
#pragma unroll
        for (int r = 0; r < 4; ++r) {
            float mx = fmaxf(fmaxf(s4[0][r], s4[1][r]), fmaxf(s4[2][r], s4[3][r]));
            mx = fmaxf(mx, __shfl_xor(mx, 1));
            mx = fmaxf(mx, __shfl_xor(mx, 2));
            mx = fmaxf(mx, __shfl_xor(mx, 4));
            mx = fmaxf(mx, __shfl_xor(mx, 8));
            const float mn = fmaxf(mrow[r], mx);
            al[r] = __expf((mrow[r] - mn) * scale);
            float ps = 0.f;
#pragma unroll
            for (int t = 0; t < 4; ++t) {
                const float p = __expf((s4[t][r] - mn) * scale);
                // P[qrow=quad*4+r][key=t*16+l15] -> chunk layout
                const int off = (((t >> 1) * 16 + quad * 4 + r) * 4 + (t & 1) * 2 + (l15 >> 3)) * 8 + (l15 & 7);
                Ps[wave * 1024 + off] = __float2bfloat16(p);
                ps += p;
            }
            ps += __shfl_xor(ps, 1);
            ps += __shfl_xor(ps, 2);
            ps += __shfl_xor(ps, 4);
            ps += __shfl_xor(ps, 8);
            lrow[r] = lrow[r] * al[r] + ps;
            mrow[r] = mn;
        }

#pragma unroll
        for (int dt = 0; dt < 8; ++dt)
#pragma unroll
            for (int r = 0; r < 4; ++r) oacc[dt][r] *= al[r];

        // P A-frags (wave-private slab, lane-contiguous reads)
        frag pa0 = *reinterpret_cast<const frag*>(&Ps[wave * 1024 + (((0*16 + l15)*4) + quad) * 8]);
        frag pa1 = *reinterpret_cast<const frag*>(&Ps[wave * 1024 + (((1*16 + l15)*4) + quad) * 8]);

        // O += P V  (V^T rows as B operand)
#pragma unroll
        for (int dt = 0; dt < 8; ++dt) {
            frag v0 = *reinterpret_cast<const frag*>(&Vt[((((dt*2+0)*16 + l15)*4) + quad) * 8]);
            frag v1 = *reinterpret_cast<const frag*>(&Vt[((((dt*2+1)*16 + l15)*4) + quad) * 8]);
            oacc[dt] = __builtin_amdgcn_mfma_f32_16x16x32_bf16(pa0, v0, oacc[dt], 0, 0, 0);
            oacc[dt] = __builtin_amdgcn_mfma_f32_16x16x32_bf16(pa1, v1, oacc[dt], 0, 0, 0);
        }
    }

#pragma unroll
    for (int r = 0; r < 4; ++r) {
        const float inv = 1.f / lrow[r];
        const int s = q0 + wave * 16 + quad * 4 + r;
        bf16* orow = attn_out + ((size_t)(b * SEQ + s)) * HID + h * HD;
#pragma unroll
        for (int dt = 0; dt < 8; ++dt)
            orow[dt * 16 + l15] = __float2bfloat16(oacc[dt][r] * inv);
    }
}

// ---------- final projection (MFMA): C(f32) = A(bf16) * Wo(f32)^T ----------
__global__ __launch_bounds__(256) void gemm_o_mfma(const bf16* __restrict__ A,
                                                   const float* __restrict__ W,
                                                   float* __restrict__ C) {
    __shared__ bf16 Asl[4096];
    __shared__ bf16 Bsl[4096];
    const int tid  = threadIdx.x;
    const int wave = tid >> 6;
    const int lane = tid & 63;
    const int quad = lane >> 4;
    const int l15  = lane & 15;
    const int row0 = blockIdx.y * 128;
    const int col0 = blockIdx.x * 128;

    const int n0 = tid, n1 = tid + 256;
    const int r0 = ((n0 >> 2) & 15) + ((n0 >> 6) << 4), c0 = (n0 & 3) * 8;
    const int r1 = ((n1 >> 2) & 15) + ((n1 >> 6) << 4), c1 = (n1 & 3) * 8;

    f32x4 acc[2][8];
#pragma unroll
    for (int i = 0; i < 2; ++i)
#pragma unroll
        for (int j = 0; j < 8; ++j) acc[i][j] = (f32x4){0.f,0.f,0.f,0.f};

    for (int k0 = 0; k0 < HID; k0 += 32) {
        __syncthreads();
        {
            // A already bf16: straight 16B copies
            *reinterpret_cast<uint4*>(&Asl[n0 * 8]) =
                *reinterpret_cast<const uint4*>(A + (size_t)(row0 + r0) * HID + k0 + c0);
            *reinterpret_cast<uint4*>(&Asl[n1 * 8]) =
                *reinterpret_cast<const uint4*>(A + (size_t)(row0 + r1) * HID + k0 + c1);
            const float4* b0 = reinterpret_cast<const float4*>(W + (size_t)(col0 + r0) * HID + k0 + c0);
            const float4* b1 = reinterpret_cast<const float4*>(W + (size_t)(col0 + r1) * HID + k0 + c1);
            cvt8_store(b0[0], b0[1], &Bsl[n0 * 8]);
            cvt8_store(b1[0], b1[1], &Bsl[n1 * 8]);
        }
        __syncthreads();
        frag af[2], bfr[8];
#pragma unroll
        for (int i = 0; i < 2; ++i)
            af[i] = *reinterpret_cast<const frag*>(&Asl[((((wave*2+i)*16 + l15)*4) + quad) * 8]);
#pragma unroll
        for (int j = 0; j < 8; ++j)
            bfr[j] = *reinterpret_cast<const frag*>(&Bsl[(((j*16 + l15)*4) + quad) * 8]);
#pragma unroll
        for (int i = 0; i < 2; ++i)
#pragma unroll
            for (int j = 0; j < 8; ++j)
                acc[i][j] = __builtin_amdgcn_mfma_f32_16x16x32_bf16(af[i], bfr[j], acc[i][j], 0, 0, 0);
    }

#pragma unroll
    for (int i = 0; i < 2; ++i)
#pragma unroll
        for (int r = 0; r < 4; ++r) {
            const int row = row0 + wave*32 + 16*i + quad*4 + r;
            float* crow = C + (size_t)row * HID + col0;
#pragma unroll
            for (int j = 0; j < 8; ++j)
                crow[16*j + l15] = acc[i][j][r];
        }
}

// ---------- launch ----------
extern "C" void kernel_launch(void* const* d_in, const int* in_sizes, int n_in,
                              void* d_out, int out_size, void* d_ws, size_t ws_size,
                              hipStream_t stream) {
    const float* hs = (const float*)d_in[0];
    const float* Wq = (const float*)d_in[1];
    const float* Wk = (const float*)d_in[2];
    const float* Wv = (const float*)d_in[3];
    const float* Wo = (const float*)d_in[4];

    float* out      = (float*)d_out;
    float* out_attn = out;                         // [B,S,H]    8388608 f32 (33.55 MB)
    float* out_k    = out + 8388608;               // [B,1,S,HD]  524288 f32
    float* out_v    = out + 8388608 + 524288;      // [B,1,S,HD]  524288 f32

    // Scratch inside d_out's attn region (consumed before gemm_o_mfma writes it):
    bf16* qbuf = (bf16*)d_out;                     // bytes 0..16.78M  roped q bf16
    bf16* kb   = (bf16*)((char*)d_out + 16777216); // bytes ..17.83M   roped k bf16
    bf16* vt   = (bf16*)((char*)d_out + 17825792); // bytes ..18.87M   v^T bf16
    bf16* attn_out = (bf16*)d_ws;                  // [B,S,H] bf16, 16.78 MB

    dim3 blk(256);
    gemm_q_mfma <<<dim3(HID/128, (BB*SEQ)/128), blk, 0, stream>>>(hs, Wq, qbuf);
    gemm_kv_mfma<<<dim3(2,       (BB*SEQ)/128), blk, 0, stream>>>(hs, Wk, Wv, out_k, out_v, kb, vt);
    attn_mfma   <<<dim3(SEQ/64, NH, BB),        blk, 0, stream>>>(qbuf, kb, vt, attn_out);
    gemm_o_mfma <<<dim3(HID/128, (BB*SEQ)/128), blk, 0, stream>>>(attn_out, Wo, out_attn);
}

// Round 10
// 525.393 us; speedup vs baseline: 19.2985x; 1.0238x over previous
//
#include <hip/hip_runtime.h>
#include <hip/hip_bf16.h>

typedef __hip_bfloat16 bf16;

#define NH   16
#define HD   128
#define SEQ  2048
#define BB   2
#define HID  2048

// ln(10000)/64
#define ROPE_C 0.14391156856f

using frag  = __attribute__((ext_vector_type(8))) short;   // 8 bf16 = 4 VGPRs
using f32x4 = __attribute__((ext_vector_type(4))) float;

// ---------- helpers ----------

// pack 8 fp32 -> 8 bf16 (one 16B LDS write)
__device__ __forceinline__ void cvt8_store(const float4 f0, const float4 f1, bf16* dst) {
    union { frag v; bf16 h[8]; } p;
    p.h[0] = __float2bfloat16(f0.x); p.h[1] = __float2bfloat16(f0.y);
    p.h[2] = __float2bfloat16(f0.z); p.h[3] = __float2bfloat16(f0.w);
    p.h[4] = __float2bfloat16(f1.x); p.h[5] = __float2bfloat16(f1.y);
    p.h[6] = __float2bfloat16(f1.z); p.h[7] = __float2bfloat16(f1.w);
    *reinterpret_cast<frag*>(dst) = p.v;
}

// pack 2 fp32 -> 1 dword of 2 bf16
__device__ __forceinline__ unsigned pk2(float a, float b) {
    union { bf16 h[2]; unsigned u; } p;
    p.h[0] = __float2bfloat16(a);
    p.h[1] = __float2bfloat16(b);
    return p.u;
}

// ---------- Q projection + fused RoPE (MFMA, unchanged from round 9) ----------
__global__ __launch_bounds__(256) void gemm_q_mfma(const float* __restrict__ A,
                                                   const float* __restrict__ W,
                                                   bf16* __restrict__ C) {
    __shared__ bf16 Asl[4096];
    __shared__ bf16 Bsl[4096];
    const int tid  = threadIdx.x;
    const int wave = tid >> 6;
    const int lane = tid & 63;
    const int quad = lane >> 4;
    const int l15  = lane & 15;
    const int row0 = blockIdx.y * 128;
    const int col0 = blockIdx.x * 128;   // = h*128

    const int n0 = tid, n1 = tid + 256;
    const int r0 = ((n0 >> 2) & 15) + ((n0 >> 6) << 4), c0 = (n0 & 3) * 8;
    const int r1 = ((n1 >> 2) & 15) + ((n1 >> 6) << 4), c1 = (n1 & 3) * 8;

    f32x4 acc[2][8];
#pragma unroll
    for (int i = 0; i < 2; ++i)
#pragma unroll
        for (int j = 0; j < 8; ++j) acc[i][j] = (f32x4){0.f,0.f,0.f,0.f};

    for (int k0 = 0; k0 < HID; k0 += 32) {
        __syncthreads();
        {
            const float4* a0 = reinterpret_cast<const float4*>(A + (size_t)(row0 + r0) * HID + k0 + c0);
            const float4* a1 = reinterpret_cast<const float4*>(A + (size_t)(row0 + r1) * HID + k0 + c1);
            const float4* b0 = reinterpret_cast<const float4*>(W + (size_t)(col0 + r0) * HID + k0 + c0);
            const float4* b1 = reinterpret_cast<const float4*>(W + (size_t)(col0 + r1) * HID + k0 + c1);
            cvt8_store(a0[0], a0[1], &Asl[n0 * 8]);
            cvt8_store(a1[0], a1[1], &Asl[n1 * 8]);
            cvt8_store(b0[0], b0[1], &Bsl[n0 * 8]);
            cvt8_store(b1[0], b1[1], &Bsl[n1 * 8]);
        }
        __syncthreads();
        frag af[2], bfr[8];
#pragma unroll
        for (int i = 0; i < 2; ++i)
            af[i] = *reinterpret_cast<const frag*>(&Asl[((((wave*2+i)*16 + l15)*4) + quad) * 8]);
#pragma unroll
        for (int j = 0; j < 8; ++j)
            bfr[j] = *reinterpret_cast<const frag*>(&Bsl[(((j*16 + l15)*4) + quad) * 8]);
#pragma unroll
        for (int i = 0; i < 2; ++i)
#pragma unroll
            for (int j = 0; j < 8; ++j)
                acc[i][j] = __builtin_amdgcn_mfma_f32_16x16x32_bf16(af[i], bfr[j], acc[i][j], 0, 0, 0);
    }

#pragma unroll
    for (int i = 0; i < 2; ++i)
#pragma unroll
        for (int r = 0; r < 4; ++r) {
            const int row = row0 + wave*32 + 16*i + quad*4 + r;
            const int s = row & (SEQ - 1);
            bf16* crow = C + (size_t)row * HID + col0;
#pragma unroll
            for (int j = 0; j < 4; ++j) {
                const int d = 16*j + l15;
                const float invf = expf(-(float)d * ROPE_C);
                float sn, cs;
                sincosf((float)s * invf, &sn, &cs);
                const float x1 = acc[i][j][r], x2 = acc[i][j+4][r];
                crow[d]      = __float2bfloat16(x1*cs - x2*sn);
                crow[d + 64] = __float2bfloat16(x2*cs + x1*sn);
            }
        }
}

// ---------- K/V projection (MFMA); K roped; fp32 outs + bf16 mirrors (unchanged) ----------
__global__ __launch_bounds__(256) void gemm_kv_mfma(const float* __restrict__ A,
                                                    const float* __restrict__ Wk,
                                                    const float* __restrict__ Wv,
                                                    float* __restrict__ Ck,
                                                    float* __restrict__ Cv,
                                                    bf16* __restrict__ kb,
                                                    bf16* __restrict__ vt) {
    __shared__ bf16 Asl[4096];
    __shared__ bf16 Bsl[4096];
    const int tid  = threadIdx.x;
    const int wave = tid >> 6;
    const int lane = tid & 63;
    const int quad = lane >> 4;
    const int l15  = lane & 15;
    const int row0 = blockIdx.y * 128;
    const bool is_v = (blockIdx.x != 0);
    const float* W = is_v ? Wv : Wk;

    const int n0 = tid, n1 = tid + 256;
    const int r0 = ((n0 >> 2) & 15) + ((n0 >> 6) << 4), c0 = (n0 & 3) * 8;
    const int r1 = ((n1 >> 2) & 15) + ((n1 >> 6) << 4), c1 = (n1 & 3) * 8;

    f32x4 acc[2][8];
#pragma unroll
    for (int i = 0; i < 2; ++i)
#pragma unroll
        for (int j = 0; j < 8; ++j) acc[i][j] = (f32x4){0.f,0.f,0.f,0.f};

    for (int k0 = 0; k0 < HID; k0 += 32) {
        __syncthreads();
        {
            const float4* a0 = reinterpret_cast<const float4*>(A + (size_t)(row0 + r0) * HID + k0 + c0);
            const float4* a1 = reinterpret_cast<const float4*>(A + (size_t)(row0 + r1) * HID + k0 + c1);
            const float4* b0 = reinterpret_cast<const float4*>(W + (size_t)r0 * HID + k0 + c0);
            const float4* b1 = reinterpret_cast<const float4*>(W + (size_t)r1 * HID + k0 + c1);
            cvt8_store(a0[0], a0[1], &Asl[n0 * 8]);
            cvt8_store(a1[0], a1[1], &Asl[n1 * 8]);
            cvt8_store(b0[0], b0[1], &Bsl[n0 * 8]);
            cvt8_store(b1[0], b1[1], &Bsl[n1 * 8]);
        }
        __syncthreads();
        frag af[2], bfr[8];
#pragma unroll
        for (int i = 0; i < 2; ++i)
            af[i] = *reinterpret_cast<const frag*>(&Asl[((((wave*2+i)*16 + l15)*4) + quad) * 8]);
#pragma unroll
        for (int j = 0; j < 8; ++j)
            bfr[j] = *reinterpret_cast<const frag*>(&Bsl[(((j*16 + l15)*4) + quad) * 8]);
#pragma unroll
        for (int i = 0; i < 2; ++i)
#pragma unroll
            for (int j = 0; j < 8; ++j)
                acc[i][j] = __builtin_amdgcn_mfma_f32_16x16x32_bf16(af[i], bfr[j], acc[i][j], 0, 0, 0);
    }

#pragma unroll
    for (int i = 0; i < 2; ++i)
#pragma unroll
        for (int r = 0; r < 4; ++r) {
            const int row = row0 + wave*32 + 16*i + quad*4 + r;   // b*SEQ + s
            const int s = row & (SEQ - 1);
            const int b = row >> 11;
            if (is_v) {
                float* crow = Cv + (size_t)row * HD;
#pragma unroll
                for (int j = 0; j < 8; ++j) {
                    const int d = 16*j + l15;
                    const float val = acc[i][j][r];
                    crow[d] = val;
                    vt[((size_t)b * HD + d) * SEQ + s] = __float2bfloat16(val);
                }
            } else {
                float* crow = Ck + (size_t)row * HD;
#pragma unroll
                for (int j = 0; j < 4; ++j) {
                    const int d = 16*j + l15;
                    const float invf = expf(-(float)d * ROPE_C);
                    float sn, cs;
                    sincosf((float)s * invf, &sn, &cs);
                    const float y1 = acc[i][j][r]*cs - acc[i][j+4][r]*sn;
                    const float y2 = acc[i][j+4][r]*cs + acc[i][j][r]*sn;
                    crow[d]      = y1;
                    crow[d + 64] = y2;
                    kb[(size_t)row * HD + d]      = __float2bfloat16(y1);
                    kb[(size_t)row * HD + d + 64] = __float2bfloat16(y2);
                }
            }
        }
}

// ---------- flash MFMA attention, S^T formulation, zero P-LDS ----------
// grid (SEQ/128, NH, B); 4 waves; wave owns 32 q-rows (2 groups of 16).
// S^T = mfma(K, Q): D row=key=quad*4+reg, col=qrow=l15 -> softmax per-lane.
// P^T C-layout -> PV B-operand via quad-permute shuffles (no LDS).
// O^T = mfma(V^T, P^T): row=dim, col=qrow.
__global__ __launch_bounds__(256) void attn_mfma(const bf16* __restrict__ qbuf,
                                                 const bf16* __restrict__ kb,
                                                 const bf16* __restrict__ vt,
                                                 bf16* __restrict__ attn_out) {
    __shared__ bf16 Ks[8192];   // 64 keys x 128 dims, chunked
    __shared__ bf16 Vt[8192];   // 128 dims x 64 keys, chunked

    const int tid  = threadIdx.x;
    const int wave = tid >> 6;
    const int lane = tid & 63;
    const int quad = lane >> 4;
    const int l15  = lane & 15;
    const int q0   = blockIdx.x * 128;
    const int h    = blockIdx.y;
    const int b    = blockIdx.z;

    const bf16* kbb = kb + (size_t)b * SEQ * HD;
    const bf16* vtb = vt + (size_t)b * HD * SEQ;

    // Q B-operand frags: qfr[g][c] = Q[qrow=w*32+g*16+l15][dims c*32+quad*8..+7]
    frag qfr[2][4];
#pragma unroll
    for (int g = 0; g < 2; ++g) {
        const bf16* qrow = qbuf + ((size_t)(b * SEQ + q0 + wave * 32 + g * 16 + l15)) * HID + h * HD;
#pragma unroll
        for (int c = 0; c < 4; ++c)
            qfr[g][c] = *reinterpret_cast<const frag*>(qrow + c * 32 + quad * 8);
    }

    // staging chunk decodes (4 chunks/thread each for K and V)
    int kkey[4], kdim[4], vdim[4], vkey[4];
#pragma unroll
    for (int i = 0; i < 4; ++i) {
        const int n = tid + i * 256;
        kkey[i] = ((n >> 2) & 15) + (((n >> 6) & 3) << 4);
        kdim[i] = ((n >> 8) << 5) + ((n & 3) << 3);
        vdim[i] = ((n >> 2) & 15) + ((n >> 7) << 4);
        vkey[i] = (((n >> 6) & 1) << 5) + ((n & 3) << 3);
    }

    f32x4 oacc[2][8];
#pragma unroll
    for (int g = 0; g < 2; ++g)
#pragma unroll
        for (int dt = 0; dt < 8; ++dt) oacc[g][dt] = (f32x4){0.f, 0.f, 0.f, 0.f};
    float mrow[2] = {-1e30f, -1e30f};
    float lrow[2] = {0.f, 0.f};
    const float scale = 0.088388347648318433f;   // 1/sqrt(128)
    const int s0lane = (quad & 1) * 32 + l15;    // src lane for j=0..3
    const int s1lane = s0lane + 16;              // src lane for j=4..7
    const bool hi_t  = (quad >> 1) != 0;         // dest quads 2,3 take t=2h+1

    for (int t0 = 0; t0 < SEQ; t0 += 64) {
        __syncthreads();
#pragma unroll
        for (int i = 0; i < 4; ++i) {
            const int n = tid + i * 256;
            *reinterpret_cast<uint4*>(&Ks[n * 8]) =
                *reinterpret_cast<const uint4*>(kbb + (size_t)(t0 + kkey[i]) * HD + kdim[i]);
            *reinterpret_cast<uint4*>(&Vt[n * 8]) =
                *reinterpret_cast<const uint4*>(vtb + (size_t)vdim[i] * SEQ + t0 + vkey[i]);
        }
        __syncthreads();

        // S^T: sacc[g][t], rows = keys t*16+quad*4+r, col = qrow l15
        f32x4 sacc[2][4];
#pragma unroll
        for (int g = 0; g < 2; ++g)
#pragma unroll
            for (int t = 0; t < 4; ++t) sacc[g][t] = (f32x4){0.f,0.f,0.f,0.f};
#pragma unroll
        for (int c = 0; c < 4; ++c) {
            frag kf[4];
#pragma unroll
            for (int t = 0; t < 4; ++t)
                kf[t] = *reinterpret_cast<const frag*>(&Ks[((((c*4+t)*16 + l15)*4) + quad) * 8]);
#pragma unroll
            for (int g = 0; g < 2; ++g)
#pragma unroll
                for (int t = 0; t < 4; ++t)
                    sacc[g][t] = __builtin_amdgcn_mfma_f32_16x16x32_bf16(kf[t], qfr[g][c], sacc[g][t], 0, 0, 0);
        }

        // softmax + P^T -> B-frag exchange, per qrow group
        float al[2];
        frag pb[2][2];
#pragma unroll
        for (int g = 0; g < 2; ++g) {
            float mx = -1e30f;
#pragma unroll
            for (int t = 0; t < 4; ++t)
#pragma unroll
                for (int r = 0; r < 4; ++r) mx = fmaxf(mx, sacc[g][t][r]);
            mx = fmaxf(mx, __shfl_xor(mx, 16));
            mx = fmaxf(mx, __shfl_xor(mx, 32));
            const float mn = fmaxf(mrow[g], mx);
            al[g] = __expf((mrow[g] - mn) * scale);
            float p[4][4];
            float ps = 0.f;
#pragma unroll
            for (int t = 0; t < 4; ++t)
#pragma unroll
                for (int r = 0; r < 4; ++r) {
                    p[t][r] = __expf((sacc[g][t][r] - mn) * scale);
                    ps += p[t][r];
                }
            ps += __shfl_xor(ps, 16);
            ps += __shfl_xor(ps, 32);
            lrow[g] = lrow[g] * al[g] + ps;
            mrow[g] = mn;

            // pack: dw[t][h2] = bf16(p[t][2h2]) | bf16(p[t][2h2+1])<<16
            unsigned dw[4][2];
#pragma unroll
            for (int t = 0; t < 4; ++t) {
                dw[t][0] = pk2(p[t][0], p[t][1]);
                dw[t][1] = pk2(p[t][2], p[t][3]);
            }
            // exchange: pb[g][half] lane(quad,l15) = keys half*32+quad*8+j, qrow l15
#pragma unroll
            for (int half = 0; half < 2; ++half) {
                const int ta = 2 * half, tb = 2 * half + 1;
                unsigned a0 = __shfl((int)dw[ta][0], s0lane);
                unsigned a1 = __shfl((int)dw[ta][1], s0lane);
                unsigned a2 = __shfl((int)dw[ta][0], s1lane);
                unsigned a3 = __shfl((int)dw[ta][1], s1lane);
                unsigned b0 = __shfl((int)dw[tb][0], s0lane);
                unsigned b1 = __shfl((int)dw[tb][1], s0lane);
                unsigned b2 = __shfl((int)dw[tb][0], s1lane);
                unsigned b3 = __shfl((int)dw[tb][1], s1lane);
                union { unsigned u[4]; frag f; } pf;
                pf.u[0] = hi_t ? b0 : a0;
                pf.u[1] = hi_t ? b1 : a1;
                pf.u[2] = hi_t ? b2 : a2;
                pf.u[3] = hi_t ? b3 : a3;
                pb[g][half] = pf.f;
            }
        }

        // rescale O^T accumulators
#pragma unroll
        for (int g = 0; g < 2; ++g)
#pragma unroll
            for (int dt = 0; dt < 8; ++dt)
#pragma unroll
                for (int r = 0; r < 4; ++r) oacc[g][dt][r] *= al[g];

        // O^T += V^T P^T
#pragma unroll
        for (int dt = 0; dt < 8; ++dt) {
            frag v0 = *reinterpret_cast<const frag*>(&Vt[((((dt*2+0)*16 + l15)*4) + quad) * 8]);
            frag v1 = *reinterpret_cast<const frag*>(&Vt[((((dt*2+1)*16 + l15)*4) + quad) * 8]);
#pragma unroll
            for (int g = 0; g < 2; ++g) {
                oacc[g][dt] = __builtin_amdgcn_mfma_f32_16x16x32_bf16(v0, pb[g][0], oacc[g][dt], 0, 0, 0);
                oacc[g][dt] = __builtin_amdgcn_mfma_f32_16x16x32_bf16(v1, pb[g][1], oacc[g][dt], 0, 0, 0);
            }
        }
    }

    // epilogue: O^T lane(quad,l15) holds qrow=w*32+g*16+l15, dims dt*16+quad*4+r
#pragma unroll
    for (int g = 0; g < 2; ++g) {
        const float inv = 1.f / lrow[g];
        const int s = q0 + wave * 32 + g * 16 + l15;
        bf16* orow = attn_out + ((size_t)(b * SEQ + s)) * HID + h * HD;
#pragma unroll
        for (int dt = 0; dt < 8; ++dt) {
            uint2 val;
            val.x = pk2(oacc[g][dt][0] * inv, oacc[g][dt][1] * inv);
            val.y = pk2(oacc[g][dt][2] * inv, oacc[g][dt][3] * inv);
            *reinterpret_cast<uint2*>(orow + dt * 16 + quad * 4) = val;
        }
    }
}

// ---------- final projection (MFMA, unchanged): C(f32) = A(bf16) * Wo(f32)^T ----------
__global__ __launch_bounds__(256) void gemm_o_mfma(const bf16* __restrict__ A,
                                                   const float* __restrict__ W,
                                                   float* __restrict__ C) {
    __shared__ bf16 Asl[4096];
    __shared__ bf16 Bsl[4096];
    const int tid  = threadIdx.x;
    const int wave = tid >> 6;
    const int lane = tid & 63;
    const int quad = lane >> 4;
    const int l15  = lane & 15;
    const int row0 = blockIdx.y * 128;
    const int col0 = blockIdx.x * 128;

    const int n0 = tid, n1 = tid + 256;
    const int r0 = ((n0 >> 2) & 15) + ((n0 >> 6) << 4), c0 = (n0 & 3) * 8;
    const int r1 = ((n1 >> 2) & 15) + ((n1 >> 6) << 4), c1 = (n1 & 3) * 8;

    f32x4 acc[2][8];
#pragma unroll
    for (int i = 0; i < 2; ++i)
#pragma unroll
        for (int j = 0; j < 8; ++j) acc[i][j] = (f32x4){0.f,0.f,0.f,0.f};

    for (int k0 = 0; k0 < HID; k0 += 32) {
        __syncthreads();
        {
            *reinterpret_cast<uint4*>(&Asl[n0 * 8]) =
                *reinterpret_cast<const uint4*>(A + (size_t)(row0 + r0) * HID + k0 + c0);
            *reinterpret_cast<uint4*>(&Asl[n1 * 8]) =
                *reinterpret_cast<const uint4*>(A + (size_t)(row0 + r1) * HID + k0 + c1);
            const float4* b0 = reinterpret_cast<const float4*>(W + (size_t)(col0 + r0) * HID + k0 + c0);
            const float4* b1 = reinterpret_cast<const float4*>(W + (size_t)(col0 + r1) * HID + k0 + c1);
            cvt8_store(b0[0], b0[1], &Bsl[n0 * 8]);
            cvt8_store(b1[0], b1[1], &Bsl[n1 * 8]);
        }
        __syncthreads();
        frag af[2], bfr[8];
#pragma unroll
        for (int i = 0; i < 2; ++i)
            af[i] = *reinterpret_cast<const frag*>(&Asl[((((wave*2+i)*16 + l15)*4) + quad) * 8]);
#pragma unroll
        for (int j = 0; j < 8; ++j)
            bfr[j] = *reinterpret_cast<const frag*>(&Bsl[(((j*16 + l15)*4) + quad) * 8]);
#pragma unroll
        for (int i = 0; i < 2; ++i)
#pragma unroll
            for (int j = 0; j < 8; ++j)
                acc[i][j] = __builtin_amdgcn_mfma_f32_16x16x32_bf16(af[i], bfr[j], acc[i][j], 0, 0, 0);
    }

#pragma unroll
    for (int i = 0; i < 2; ++i)
#pragma unroll
        for (int r = 0; r < 4; ++r) {
            const int row = row0 + wave*32 + 16*i + quad*4 + r;
            float* crow = C + (size_t)row * HID + col0;
#pragma unroll
            for (int j = 0; j < 8; ++j)
                crow[16*j + l15] = acc[i][j][r];
        }
}

// ---------- launch ----------
extern "C" void kernel_launch(void* const* d_in, const int* in_sizes, int n_in,
                              void* d_out, int out_size, void* d_ws, size_t ws_size,
                              hipStream_t stream) {
    const float* hs = (const float*)d_in[0];
    const float* Wq = (const float*)d_in[1];
    const float* Wk = (const float*)d_in[2];
    const float* Wv = (const float*)d_in[3];
    const float* Wo = (const float*)d_in[4];

    float* out      = (float*)d_out;
    float* out_attn = out;                         // [B,S,H]    8388608 f32 (33.55 MB)
    float* out_k    = out + 8388608;               // [B,1,S,HD]  524288 f32
    float* out_v    = out + 8388608 + 524288;      // [B,1,S,HD]  524288 f32

    // Scratch inside d_out's attn region (consumed before gemm_o_mfma writes it):
    bf16* qbuf = (bf16*)d_out;                     // bytes 0..16.78M  roped q bf16
    bf16* kb   = (bf16*)((char*)d_out + 16777216); // bytes ..17.83M   roped k bf16
    bf16* vt   = (bf16*)((char*)d_out + 17825792); // bytes ..18.87M   v^T bf16
    bf16* attn_out = (bf16*)d_ws;                  // [B,S,H] bf16, 16.78 MB

    dim3 blk(256);
    gemm_q_mfma <<<dim3(HID/128, (BB*SEQ)/128), blk, 0, stream>>>(hs, Wq, qbuf);
    gemm_kv_mfma<<<dim3(2,       (BB*SEQ)/128), blk, 0, stream>>>(hs, Wk, Wv, out_k, out_v, kb, vt);
    attn_mfma   <<<dim3(SEQ/128, NH, BB),       blk, 0, stream>>>(qbuf, kb, vt, attn_out);
    gemm_o_mfma <<<dim3(HID/128, (BB*SEQ)/128), blk, 0, stream>>>(attn_out, Wo, out_attn);
}